// Round 8
// baseline (439.571 us; speedup 1.0000x reference)
//
#include <hip/hip_runtime.h>

#define DECAYF 0.99f
#define ONEMF 0.01f
#define EPSF 1e-5f

typedef __bf16 bf16x8 __attribute__((ext_vector_type(8)));
typedef float f32x4 __attribute__((ext_vector_type(4)));
typedef unsigned short ushort8 __attribute__((ext_vector_type(8)));

// ws float layout:
// [0, 1048576)            dw accumulator, 16 replicas of K*D
// [1048576, 1064960)      counts, 16 replicas of K
// [1064960, 1065984)      nchalf = -0.5*||e_k||^2
// [1065984]               sse
// [1066000, 1131536)      idx (int) per token
// [1131536, 1164304)      E_hi bf16 plane (ushort [K][64])
// [1164304, 1197072)      E_lo bf16 plane
// [1197072, 3294224)      per-panel top2: [token][panel][s1,c1,s2,c2]
#define WS_DW     0
#define WS_COUNTS 1048576
#define WS_NCHALF 1064960
#define WS_SSE    1065984
#define WS_IDX    1066000
#define WS_EHI    1131536
#define WS_ELO    1164304
#define WS_TOP2   1197072

__device__ __forceinline__ float wave_reduce_add(float v) {
#pragma unroll
    for (int o = 32; o > 0; o >>= 1) v += __shfl_xor(v, o, 64);
    return v;
}

__device__ __forceinline__ unsigned short bf_rne(float f) {
    unsigned int u = __float_as_uint(f);
    unsigned int r = u + 0x7fffu + ((u >> 16) & 1u);
    return (unsigned short)(r >> 16);
}

// E split (hi/lo bf16 planes) + nchalf. grid 256 x 256.
__global__ __launch_bounds__(256) void prep_kernel(const float* __restrict__ E,
                                                   float* __restrict__ ws) {
    const int id = blockIdx.x * 256 + threadIdx.x;
    const float v = E[id];
    const unsigned short h = bf_rne(v);
    const float hf = __uint_as_float((unsigned int)h << 16);
    const unsigned short l = bf_rne(v - hf);
    ((unsigned short*)(ws + WS_EHI))[id] = h;
    ((unsigned short*)(ws + WS_ELO))[id] = l;
    const float s = wave_reduce_add(v * v);
    if ((threadIdx.x & 63) == 0) ws[WS_NCHALF + (id >> 6)] = -0.5f * s;
}

// LDS-tiled score pass. grid 4096 (= 512 token-tiles x 8 panels) x 256.
// Block: 128 tokens x 128 codes; zero global loads in the MFMA loop.
__global__ __launch_bounds__(256, 2) void vq_panel(const float* __restrict__ x,
                                                   float* __restrict__ ws) {
    const int tid = threadIdx.x;
    const int lane = tid & 63;
    const int w = tid >> 6;           // wave 0..3: tokens w*32..+32
    const int q = lane >> 4, m = lane & 15;
    const int bx = blockIdx.x;
    const int tb = bx >> 3;           // token tile
    const int pb = bx & 7;            // code panel
    const int bb = tb >> 5;
    const int hw0 = (tb & 31) << 7;
    const int tok0 = tb << 7;
    const int k0 = pb << 7;

    // Row stride 72 ushorts (144B): b128-aligned rows, staging conflicts 8-way.
    __shared__ __align__(16) unsigned short Ash[128 * 72];
    __shared__ __align__(16) unsigned short Asl[128 * 72];
    __shared__ __align__(16) unsigned short Bsh[128 * 72];
    __shared__ __align__(16) unsigned short Bsl[128 * 72];

    // Stage B panel from pre-split planes (b128 chunks, coalesced).
    {
        const ushort8* __restrict__ Eh = (const ushort8*)(ws + WS_EHI);
        const ushort8* __restrict__ El = (const ushort8*)(ws + WS_ELO);
#pragma unroll
        for (int i = 0; i < 4; ++i) {
            const int idx = i * 256 + tid;
            const int row = idx >> 3, ch = idx & 7;
            *(ushort8*)&Bsh[row * 72 + ch * 8] = Eh[(k0 + row) * 8 + ch];
            *(ushort8*)&Bsl[row * 72 + ch * 8] = El[(k0 + row) * 8 + ch];
        }
    }
    // Stage A tile from x (coalesced reads), hi/lo split in-flight.
    {
        const float* xb = x + ((size_t)bb << 18) + hw0;
#pragma unroll
        for (int i = 0; i < 32; ++i) {
            const int idx = i * 256 + tid;
            const int c = idx >> 7, t = idx & 127;
            const float f = xb[((size_t)c << 12) + t];
            const unsigned short h = bf_rne(f);
            const float hf = __uint_as_float((unsigned int)h << 16);
            Ash[t * 72 + c] = h;
            Asl[t * 72 + c] = bf_rne(f - hf);
        }
    }
    __syncthreads();

    // A fragments (kept in registers for all 8 col-tiles).
    bf16x8 Ah[2][2], Al[2][2];
#pragma unroll
    for (int t2 = 0; t2 < 2; ++t2) {
        const int tok = w * 32 + t2 * 16 + m;
#pragma unroll
        for (int s = 0; s < 2; ++s) {
            Ah[t2][s] = __builtin_bit_cast(bf16x8, *(const ushort8*)&Ash[tok * 72 + s * 32 + q * 8]);
            Al[t2][s] = __builtin_bit_cast(bf16x8, *(const ushort8*)&Asl[tok * 72 + s * 32 + q * 8]);
        }
    }

    const float* __restrict__ ncp = ws + WS_NCHALF + k0;

    float s1[2][4], s2[2][4];
    int i1[2][4], i2[2][4];
#pragma unroll
    for (int t2 = 0; t2 < 2; ++t2)
#pragma unroll
        for (int r = 0; r < 4; ++r) { s1[t2][r] = -1e30f; s2[t2][r] = -1e30f; i1[t2][r] = 0; i2[t2][r] = 0; }

#pragma unroll 2
    for (int ct = 0; ct < 8; ++ct) {
        const int crow = ct * 16 + m;
        const bf16x8 Bh0 = __builtin_bit_cast(bf16x8, *(const ushort8*)&Bsh[crow * 72 + q * 8]);
        const bf16x8 Bh1 = __builtin_bit_cast(bf16x8, *(const ushort8*)&Bsh[crow * 72 + 32 + q * 8]);
        const bf16x8 Bl0 = __builtin_bit_cast(bf16x8, *(const ushort8*)&Bsl[crow * 72 + q * 8]);
        const bf16x8 Bl1 = __builtin_bit_cast(bf16x8, *(const ushort8*)&Bsl[crow * 72 + 32 + q * 8]);
        const float base = ncp[crow];
        const int code = k0 + crow;
#pragma unroll
        for (int t2 = 0; t2 < 2; ++t2) {
            f32x4 acc = {base, base, base, base};  // x.e - 0.5||e||^2
            acc = __builtin_amdgcn_mfma_f32_16x16x32_bf16(Ah[t2][0], Bh0, acc, 0, 0, 0);
            acc = __builtin_amdgcn_mfma_f32_16x16x32_bf16(Ah[t2][1], Bh1, acc, 0, 0, 0);
            acc = __builtin_amdgcn_mfma_f32_16x16x32_bf16(Al[t2][0], Bh0, acc, 0, 0, 0);
            acc = __builtin_amdgcn_mfma_f32_16x16x32_bf16(Al[t2][1], Bh1, acc, 0, 0, 0);
            acc = __builtin_amdgcn_mfma_f32_16x16x32_bf16(Ah[t2][0], Bl0, acc, 0, 0, 0);
            acc = __builtin_amdgcn_mfma_f32_16x16x32_bf16(Ah[t2][1], Bl1, acc, 0, 0, 0);
#pragma unroll
            for (int r = 0; r < 4; ++r) {
                const float sc = acc[r];
                const bool cA = sc > s1[t2][r];
                const bool cB = sc > s2[t2][r];
                s2[t2][r] = cA ? s1[t2][r] : (cB ? sc : s2[t2][r]);
                i2[t2][r] = cA ? i1[t2][r] : (cB ? code : i2[t2][r]);
                s1[t2][r] = cA ? sc : s1[t2][r];
                i1[t2][r] = cA ? code : i1[t2][r];
            }
        }
    }

    // Merge top-2 across the 16 columns (lanes of each q group).
#pragma unroll
    for (int d = 1; d < 16; d <<= 1) {
#pragma unroll
        for (int t2 = 0; t2 < 2; ++t2)
#pragma unroll
            for (int r = 0; r < 4; ++r) {
                const float o1 = __shfl_xor(s1[t2][r], d, 64);
                const int   oc1 = __shfl_xor(i1[t2][r], d, 64);
                const float o2 = __shfl_xor(s2[t2][r], d, 64);
                const int   oc2 = __shfl_xor(i2[t2][r], d, 64);
                const bool win = o1 > s1[t2][r];
                const float n1 = win ? o1 : s1[t2][r]; const int nc1 = win ? oc1 : i1[t2][r];
                const float ls = win ? s1[t2][r] : o1; const int lc = win ? i1[t2][r] : oc1;
                const float os = win ? o2 : s2[t2][r]; const int oc = win ? oc2 : i2[t2][r];
                const bool sec = ls > os;
                s1[t2][r] = n1; i1[t2][r] = nc1;
                s2[t2][r] = sec ? ls : os; i2[t2][r] = sec ? lc : oc;
            }
    }
    if (m == 0) {
        float* tp = ws + WS_TOP2;
#pragma unroll
        for (int t2 = 0; t2 < 2; ++t2)
#pragma unroll
            for (int r = 0; r < 4; ++r) {
                const int tokL = w * 32 + t2 * 16 + q * 4 + r;
                f32x4 v;
                v[0] = s1[t2][r]; v[1] = __int_as_float(i1[t2][r]);
                v[2] = s2[t2][r]; v[3] = __int_as_float(i2[t2][r]);
                *(f32x4*)&tp[((size_t)(tok0 + tokL) * 8 + pb) * 4] = v;
            }
    }
}

// Merge 8 panels per token + fp64 re-rank + idx/counts/sse. grid 256 x 256.
__global__ __launch_bounds__(256) void vq_merge(const float* __restrict__ x,
                                                const float* __restrict__ E,
                                                float* __restrict__ ws) {
    const int tid = threadIdx.x;
    const int token = blockIdx.x * 256 + tid;
    const f32x4* tp = (const f32x4*)(ws + WS_TOP2 + (size_t)token * 32);
    float s1 = -1e30f, s2 = -1e30f;
    int c1 = 0, c2 = 1;
#pragma unroll
    for (int p = 0; p < 8; ++p) {
        const f32x4 v = tp[p];
        const float a = v[0]; const int ac = __float_as_int(v[1]);
        const float b = v[2]; const int bc = __float_as_int(v[3]);
        if (a > s1) { s2 = s1; c2 = c1; s1 = a; c1 = ac; }
        else if (a > s2) { s2 = a; c2 = ac; }
        if (b > s2) { s2 = b; c2 = bc; }
    }
    const int ca = c1 < c2 ? c1 : c2;
    const int cb = c1 < c2 ? c2 : c1;
    const int bb = token >> 12;
    const int hw = token & 4095;
    const float* xb = x + ((size_t)bb << 18) + hw;   // stride-4096 dims, coalesced per dim
    const f32x4* Ea4 = (const f32x4*)(E + ca * 64);
    const f32x4* Eb4 = (const f32x4*)(E + cb * 64);
    double sa = 0, ea = 0, sb = 0, eb = 0, x2 = 0;
#pragma unroll 4
    for (int c4 = 0; c4 < 16; ++c4) {
        const f32x4 ev = Ea4[c4], fv = Eb4[c4];
#pragma unroll
        for (int j = 0; j < 4; ++j) {
            const double xv = (double)xb[(size_t)(c4 * 4 + j) << 12];
            const double va = (double)ev[j], vb = (double)fv[j];
            sa += xv * va; ea += va * va;
            sb += xv * vb; eb += vb * vb;
            x2 += xv * xv;
        }
    }
    const double qa = ea - 2.0 * sa;
    const double qb = eb - 2.0 * sb;
    int best; double qq;
    if (qb < qa) { best = cb; qq = qb; } else { best = ca; qq = qa; }
    ((int*)(ws + WS_IDX))[token] = best;
    float dd = (float)(qq + x2);
    if (dd < 0.f) dd = 0.f;
    atomicAdd(&ws[WS_COUNTS + (blockIdx.x & 15) * 1024 + best], 1.0f);
    const float ssum = wave_reduce_add(dd);
    __shared__ float red[4];
    if ((tid & 63) == 0) red[tid >> 6] = ssum;
    __syncthreads();
    if (tid == 0) atomicAdd(&ws[WS_SSE], red[0] + red[1] + red[2] + red[3]);
}

// q_st + dw. grid 512 x 256; block = 128 tokens.
__global__ __launch_bounds__(256) void qst_dw(const float* __restrict__ x,
                                              const float* __restrict__ E,
                                              float* __restrict__ out,
                                              float* __restrict__ ws) {
    const int tid = threadIdx.x;
    const int lane = tid & 63;
    const int w = tid >> 6;
    const int blk = blockIdx.x;
    const int bb = blk >> 5;
    const int hw0 = (blk & 31) << 7;
    const int tok0 = blk << 7;

    __shared__ float xs[128 * 65];
    __shared__ float qs[128 * 65];
    __shared__ int idx_sh[128];

    if (tid < 128) idx_sh[tid] = ((const int*)(ws + WS_IDX))[tok0 + tid];
    {
        const float* xb = x + ((size_t)bb << 18) + hw0;
#pragma unroll
        for (int cc = 0; cc < 32; ++cc) {
            const int id = cc * 256 + tid;
            const int c = id >> 7, t = id & 127;
            xs[t * 65 + c] = xb[((size_t)c << 12) + t];
        }
    }
    __syncthreads();
    {
        float* dwr = ws + WS_DW + (size_t)(blk & 15) * 65536;
#pragma unroll 4
        for (int tt = 0; tt < 32; ++tt) {
            const int t = w * 32 + tt;
            const int kb = idx_sh[t];
            qs[t * 65 + lane] = E[kb * 64 + lane];
            atomicAdd(&dwr[kb * 64 + lane], xs[t * 65 + lane]);
        }
    }
    __syncthreads();
    float* outq = out + 1;
#pragma unroll
    for (int cc = 0; cc < 32; ++cc) {
        const int id = cc * 256 + tid;
        const int c = id >> 7, t = id & 127;
        const float xv = xs[t * 65 + c];
        const float eq = qs[t * 65 + c];
        outq[((size_t)(bb * 64 + c) << 12) + hw0 + t] = xv + (eq - xv);
    }
}

// Pure-store one-hot writer. grid 2048 x 256.
__global__ __launch_bounds__(256) void enc_write(const float* __restrict__ ws,
                                                 float* __restrict__ out) {
    const int tid = threadIdx.x;
    const int c0 = tid << 2;
    const int row0 = blockIdx.x << 5;
    const int* __restrict__ idxp = (const int*)(ws + WS_IDX);
    float* enc = out + 1 + (size_t)4194304;
    for (int r = 0; r < 32; ++r) {
        const int row = row0 + r;
        const int kb = idxp[row];
        f32x4 v;
        v[0] = (c0 == kb) ? 1.0f : 0.0f;
        v[1] = (c0 + 1 == kb) ? 1.0f : 0.0f;
        v[2] = (c0 + 2 == kb) ? 1.0f : 0.0f;
        v[3] = (c0 + 3 == kb) ? 1.0f : 0.0f;
        *(f32x4*)(enc + (size_t)row * 1024 + c0) = v;
    }
}

// new_cs (Laplace-smoothed, 16 count replicas) + loss. 1 block x 1024.
__global__ __launch_bounds__(1024) void fin_cs(const float* __restrict__ cs_in,
                                               float* __restrict__ out,
                                               const float* __restrict__ ws) {
    __shared__ float red[16];
    __shared__ float n_sh;
    const int tid = threadIdx.x;
    float cnt = 0.f;
#pragma unroll
    for (int p = 0; p < 16; ++p) cnt += ws[WS_COUNTS + p * 1024 + tid];
    const float raw = cs_in[tid] * DECAYF + ONEMF * cnt;
    const float s = wave_reduce_add(raw);
    if ((tid & 63) == 0) red[tid >> 6] = s;
    __syncthreads();
    if (tid == 0) {
        float n = 0.f;
#pragma unroll
        for (int i = 0; i < 16; ++i) n += red[i];
        n_sh = n;
        out[0] = 0.25f * ws[WS_SSE] * (1.0f / 4194304.0f);
    }
    __syncthreads();
    const float n = n_sh;
    out[71368705 + tid] = (raw + EPSF) / (n + 1024.0f * EPSF) * n;
}

// new_ema_weight and new_embedding (reduce 16 dw replicas). grid 256 x 256.
__global__ __launch_bounds__(256) void fin_w(const float* __restrict__ emaw,
                                             float* __restrict__ out,
                                             const float* __restrict__ ws) {
    const int i = blockIdx.x * 256 + threadIdx.x;
    float acc = 0.f;
#pragma unroll
    for (int p = 0; p < 16; ++p) acc += ws[WS_DW + p * 65536 + i];
    const float val = emaw[i] * DECAYF + ONEMF * acc;
    out[71369729 + i] = val;
    const float cs = out[71368705 + (i >> 6)];
    out[71303169 + i] = val / cs;
}

extern "C" void kernel_launch(void* const* d_in, const int* in_sizes, int n_in,
                              void* d_out, int out_size, void* d_ws, size_t ws_size,
                              hipStream_t stream) {
    const float* x    = (const float*)d_in[0];
    const float* E    = (const float*)d_in[1];
    const float* cs   = (const float*)d_in[2];
    const float* emaw = (const float*)d_in[3];
    float* out = (float*)d_out;
    float* ws  = (float*)d_ws;

    hipMemsetAsync(ws, 0, (size_t)(WS_SSE + 1) * sizeof(float), stream);
    prep_kernel<<<256, 256, 0, stream>>>(E, ws);
    vq_panel<<<4096, 256, 0, stream>>>(x, ws);
    vq_merge<<<256, 256, 0, stream>>>(x, E, ws);
    qst_dw<<<512, 256, 0, stream>>>(x, E, out, ws);
    enc_write<<<2048, 256, 0, stream>>>(ws, out);
    fin_cs<<<1, 1024, 0, stream>>>(cs, out, ws);
    fin_w<<<256, 256, 0, stream>>>(emaw, out, ws);
}